// Round 1
// baseline (1736.959 us; speedup 1.0000x reference)
//
#include <hip/hip_runtime.h>
#include <hip/hip_bf16.h>
#include <cmath>

#define CDIM 256
#define TPW 49
#define NWIN 1024
#define MTOK (NWIN * TPW)   // 50176 tokens (windowed order)
#define NHEAD 8
#define GH 224
#define GW 56
#define MCHUNK 12544        // MTOK / 4

__device__ __forceinline__ void store_val(float* p, float v) { *p = v; }
__device__ __forceinline__ void store_val(__hip_bfloat16* p, float v) { *p = __float2bfloat16(v); }

__device__ __forceinline__ float wave_sum(float v) {
    v += __shfl_down(v, 32);
    v += __shfl_down(v, 16);
    v += __shfl_down(v, 8);
    v += __shfl_down(v, 4);
    v += __shfl_down(v, 2);
    v += __shfl_down(v, 1);
    return v;
}

// 256-thread block sum * (1/256); red must be __shared__ float[8]
__device__ __forceinline__ float block_mean_256(float v, float* red, int tid) {
    float s = wave_sum(v);
    if ((tid & 63) == 0) red[tid >> 6] = s;
    __syncthreads();
    if (tid == 0) red[4] = (red[0] + red[1] + red[2] + red[3]) * (1.0f / 256.0f);
    __syncthreads();
    return red[4];
}

// LN over C=256 fused with roll(-3,-3) + 7x7 window partition gather.
// Block = one windowed token (256 ch). out[t*256+c] in windowed order.
__global__ __launch_bounds__(256) void ln1_window_kernel(
    const float* __restrict__ x1, const float* __restrict__ g,
    const float* __restrict__ b, float* __restrict__ out)
{
    __shared__ float red[8];
    const int t = blockIdx.x;
    const int c = threadIdx.x;
    const int bw = t / TPW, n = t - bw * TPW;
    const int bb = bw >> 8, wi = bw & 255;      // 256 windows per batch
    const int hb = wi >> 3, wb = wi & 7;
    const int i = n / 7, j = n - i * 7;
    int h0 = hb * 7 + i + 3; if (h0 >= GH) h0 -= GH;   // roll by -3 => source = +3
    int w0 = wb * 7 + j + 3; if (w0 >= GW) w0 -= GW;
    const long src = ((long)(bb * GH + h0) * GW + w0) * CDIM + c;
    const float v = x1[src];
    const float mean = block_mean_256(v, red, c);
    const float d = v - mean;
    const float var = block_mean_256(d * d, red, c);
    out[(long)t * CDIM + c] = d * rsqrtf(var + 1e-5f) * g[c] + b[c];
}

// Plain LN over C=256. Block = one token.
__global__ __launch_bounds__(256) void ln_kernel(
    const float* __restrict__ x, const float* __restrict__ g,
    const float* __restrict__ b, float* __restrict__ out)
{
    __shared__ float red[8];
    const int t = blockIdx.x;
    const int c = threadIdx.x;
    const float v = x[(long)t * CDIM + c];
    const float mean = block_mean_256(v, red, c);
    const float d = v - mean;
    const float var = block_mean_256(d * d, red, c);
    out[(long)t * CDIM + c] = d * rsqrtf(var + 1e-5f) * g[c] + b[c];
}

// Y[m,n] = sum_k X[m,k] * W[n,k] + bias[n]; EPI: 0=none, 1=GELU, 2=+res
// 64x64 tile, BK=16, 256 threads, 4x4 per thread. M,Nout,K all multiples of 64/16.
template <int EPI, typename OutT>
__global__ __launch_bounds__(256) void gemm_wt(
    const float* __restrict__ X, const float* __restrict__ W,
    const float* __restrict__ bias, OutT* __restrict__ Y,
    int M, int K, int Nout, const float* __restrict__ res)
{
    __shared__ float Xs[16][64];
    __shared__ float Ws[16][64];
    const int bm = blockIdx.y * 64;
    const int bn = blockIdx.x * 64;
    const int tid = threadIdx.x;
    const int tm = (tid >> 4) << 2;
    const int tn = (tid & 15) << 2;
    const int lr = tid >> 2;            // 0..63
    const int lk = (tid & 3) << 2;      // 0,4,8,12
    float acc[4][4] = {};
    const float* Xp = X + (long)(bm + lr) * K + lk;
    const float* Wp = W + (long)(bn + lr) * K + lk;
    for (int k0 = 0; k0 < K; k0 += 16) {
        const float4 xv = *(const float4*)(Xp + k0);
        const float4 wv = *(const float4*)(Wp + k0);
        Xs[lk + 0][lr] = xv.x; Xs[lk + 1][lr] = xv.y;
        Xs[lk + 2][lr] = xv.z; Xs[lk + 3][lr] = xv.w;
        Ws[lk + 0][lr] = wv.x; Ws[lk + 1][lr] = wv.y;
        Ws[lk + 2][lr] = wv.z; Ws[lk + 3][lr] = wv.w;
        __syncthreads();
#pragma unroll
        for (int k = 0; k < 16; ++k) {
            const float4 av = *(const float4*)&Xs[k][tm];
            const float4 bv = *(const float4*)&Ws[k][tn];
            acc[0][0] += av.x * bv.x; acc[0][1] += av.x * bv.y; acc[0][2] += av.x * bv.z; acc[0][3] += av.x * bv.w;
            acc[1][0] += av.y * bv.x; acc[1][1] += av.y * bv.y; acc[1][2] += av.y * bv.z; acc[1][3] += av.y * bv.w;
            acc[2][0] += av.z * bv.x; acc[2][1] += av.z * bv.y; acc[2][2] += av.z * bv.z; acc[2][3] += av.z * bv.w;
            acc[3][0] += av.w * bv.x; acc[3][1] += av.w * bv.y; acc[3][2] += av.w * bv.z; acc[3][3] += av.w * bv.w;
        }
        __syncthreads();
    }
#pragma unroll
    for (int i = 0; i < 4; ++i) {
        const long row = bm + tm + i;
#pragma unroll
        for (int j = 0; j < 4; ++j) {
            const int col = bn + tn + j;
            float v = acc[i][j] + bias[col];
            if (EPI == 1) v = 0.5f * v * (1.0f + erff(v * 0.70710678118654752f));
            if (EPI == 2) v += res[row * Nout + col];
            store_val(&Y[row * Nout + col], v);
        }
    }
}

// One block per (window, head). qkv: bf16 (MTOK, 768) with feature = s*256+h*32+d.
// Writes yout (MTOK, 256) fp32 at feature h*32+d (windowed token order).
__global__ __launch_bounds__(256) void attn_kernel(
    const __hip_bfloat16* __restrict__ qkv,
    const float* __restrict__ rpb,     // (169, 8)
    float* __restrict__ yout)
{
    __shared__ float qs[49][32], ks[49][32], vs[49][32];
    __shared__ float sc[49][49];
    const int blk = blockIdx.x;
    const int bw = blk >> 3;
    const int head = blk & 7;
    const int tid = threadIdx.x;
    const int wi = bw & 255;
    const int hb = wi >> 3, wb = wi & 7;

    const __hip_bfloat16* base = qkv + (long)bw * TPW * 768 + head * 32;
    for (int e = tid; e < 49 * 32; e += 256) {
        const int n = e >> 5, d = e & 31;
        const long o = (long)n * 768 + d;
        qs[n][d] = __bfloat162float(base[o]) * 0.17677669529663687f;  // 1/sqrt(32)
        ks[n][d] = __bfloat162float(base[o + 256]);
        vs[n][d] = __bfloat162float(base[o + 512]);
    }
    __syncthreads();

    for (int e = tid; e < 49 * 49; e += 256) {
        const int n = e / 49, m = e - n * 49;
        float acc = 0.0f;
#pragma unroll
        for (int dd = 0; dd < 32; dd += 4) {
            const float4 qa = *(const float4*)&qs[n][dd];
            const float4 ka = *(const float4*)&ks[m][dd];
            acc += qa.x * ka.x + qa.y * ka.y + qa.z * ka.z + qa.w * ka.w;
        }
        const int in_ = n / 7, jn = n - in_ * 7;
        const int im = m / 7, jm = m - im * 7;
        acc += rpb[((in_ - im + 6) * 13 + (jn - jm + 6)) * 8 + head];
        // shift mask: regions on (224,56) grid, h: [0,217)[217,221)[221,224), w: [0,49)[49,53)[53,56)
        const int hn = hb * 7 + in_, wn = wb * 7 + jn;
        const int hm = hb * 7 + im, wm = wb * 7 + jm;
        const int rn = (hn < 217 ? 0 : (hn < 221 ? 3 : 6)) + (wn < 49 ? 0 : (wn < 53 ? 1 : 2));
        const int rm = (hm < 217 ? 0 : (hm < 221 ? 3 : 6)) + (wm < 49 ? 0 : (wm < 53 ? 1 : 2));
        if (rn != rm) acc -= 100.0f;
        sc[n][m] = acc;
    }
    __syncthreads();

    if (tid < 49) {
        float mx = -1e30f;
        for (int m = 0; m < 49; ++m) mx = fmaxf(mx, sc[tid][m]);
        float sum = 0.0f;
        for (int m = 0; m < 49; ++m) { const float e = __expf(sc[tid][m] - mx); sc[tid][m] = e; sum += e; }
        const float inv = 1.0f / sum;
        for (int m = 0; m < 49; ++m) sc[tid][m] *= inv;
    }
    __syncthreads();

    for (int e = tid; e < 49 * 8; e += 256) {
        const int n = e >> 3, d4 = (e & 7) << 2;
        float4 a = {0.f, 0.f, 0.f, 0.f};
        for (int m = 0; m < 49; ++m) {
            const float p = sc[n][m];
            const float4 vv = *(const float4*)&vs[m][d4];
            a.x += p * vv.x; a.y += p * vv.y; a.z += p * vv.z; a.w += p * vv.w;
        }
        const long o = ((long)bw * TPW + n) * CDIM + head * 32 + d4;
        *(float4*)&yout[o] = a;
    }
}

// Window-reverse + roll(+3,+3) scatter; writes out2 (= attention branch output)
// and x1b = x1 + y. Block = one windowed token.
__global__ __launch_bounds__(256) void scatter_kernel(
    const float* __restrict__ yproj, const float* __restrict__ x1,
    float* __restrict__ out2, float* __restrict__ x1b)
{
    const int t = blockIdx.x;
    const int c = threadIdx.x;
    const int bw = t / TPW, n = t - bw * TPW;
    const int bb = bw >> 8, wi = bw & 255;
    const int hb = wi >> 3, wb = wi & 7;
    const int i = n / 7, j = n - i * 7;
    int h0 = hb * 7 + i + 3; if (h0 >= GH) h0 -= GH;
    int w0 = wb * 7 + j + 3; if (w0 >= GW) w0 -= GW;
    const long dst = ((long)bb * (GH * GW) + h0 * GW + w0) * CDIM + c;
    const float y = yproj[(long)t * CDIM + c];
    out2[dst] = y;
    x1b[dst] = x1[dst] + y;
}

extern "C" void kernel_launch(void* const* d_in, const int* in_sizes, int n_in,
                              void* d_out, int out_size, void* d_ws, size_t ws_size,
                              hipStream_t stream) {
    (void)in_sizes; (void)n_in; (void)out_size; (void)ws_size;
    const float* x1     = (const float*)d_in[0];
    const float* n1g    = (const float*)d_in[2];
    const float* n1b    = (const float*)d_in[3];
    const float* qkv_w  = (const float*)d_in[4];
    const float* qkv_b  = (const float*)d_in[5];
    const float* proj_w = (const float*)d_in[6];
    const float* proj_b = (const float*)d_in[7];
    const float* rpb    = (const float*)d_in[8];
    const float* n2g    = (const float*)d_in[9];
    const float* n2b    = (const float*)d_in[10];
    const float* fc1_w  = (const float*)d_in[11];
    const float* fc1_b  = (const float*)d_in[12];
    const float* fc2_w  = (const float*)d_in[13];
    const float* fc2_b  = (const float*)d_in[14];

    float* out_x1 = (float*)d_out;                       // first output: x1_new
    float* out_y  = out_x1 + (long)MTOK * CDIM;          // second output: attn branch

    char* ws = (char*)d_ws;
    const size_t SZ_A = (size_t)MTOK * CDIM * sizeof(float);   // 51,380,224 B
    float* A = (float*)ws;                 // xw -> yw -> hn (reused)
    float* D = (float*)(ws + SZ_A);        // x1b
    char*  Q = ws + 2 * SZ_A;              // qkv(bf16) -> yproj -> h1 chunks (77 MB region)
    __hip_bfloat16* qkvbuf = (__hip_bfloat16*)Q;
    float* P = (float*)Q;
    float* Hbuf = (float*)Q;

    // 1) LN1 + roll + window partition
    ln1_window_kernel<<<MTOK, 256, 0, stream>>>(x1, n1g, n1b, A);
    // 2) QKV gemm -> bf16
    gemm_wt<0, __hip_bfloat16><<<dim3(768 / 64, MTOK / 64), 256, 0, stream>>>(
        A, qkv_w, qkv_b, qkvbuf, MTOK, CDIM, 768, nullptr);
    // 3) windowed attention
    attn_kernel<<<NWIN * NHEAD, 256, 0, stream>>>(qkvbuf, rpb, A);
    // 4) proj
    gemm_wt<0, float><<<dim3(256 / 64, MTOK / 64), 256, 0, stream>>>(
        A, proj_w, proj_b, P, MTOK, CDIM, CDIM, nullptr);
    // 5) reverse windows + unshift + residual; writes out_y and x1b
    scatter_kernel<<<MTOK, 256, 0, stream>>>(P, x1, out_y, D);
    // 6) LN2
    ln_kernel<<<MTOK, 256, 0, stream>>>(D, n2g, n2b, A);
    // 7) MLP in 4 chunks (bounds scratch to one 51 MB h1 buffer)
    for (int ch = 0; ch < 4; ++ch) {
        const long off = (long)ch * MCHUNK;
        gemm_wt<1, float><<<dim3(1024 / 64, MCHUNK / 64), 256, 0, stream>>>(
            A + off * CDIM, fc1_w, fc1_b, Hbuf, MCHUNK, CDIM, 1024, nullptr);
        gemm_wt<2, float><<<dim3(256 / 64, MCHUNK / 64), 256, 0, stream>>>(
            Hbuf, fc2_w, fc2_b, out_x1 + off * CDIM, MCHUNK, 1024, CDIM, D + off * CDIM);
    }
}

// Round 2
// 684.038 us; speedup vs baseline: 2.5393x; 2.5393x over previous
//
#include <hip/hip_runtime.h>
#include <hip/hip_bf16.h>
#include <cmath>

#define CDIM 256
#define TPW 49
#define NWIN 1024
#define MTOK (NWIN * TPW)   // 50176 tokens (windowed order)
#define NHEAD 8
#define GH 224
#define GW 56

typedef __attribute__((ext_vector_type(8))) __bf16 bf16x8;
typedef __attribute__((ext_vector_type(4))) float f32x4;

__device__ __forceinline__ void store_val(float* p, float v) { *p = v; }
__device__ __forceinline__ void store_val(__hip_bfloat16* p, float v) { *p = __float2bfloat16(v); }

__device__ __forceinline__ void async_copy16(const void* g, void* l) {
    __builtin_amdgcn_global_load_lds(
        (const __attribute__((address_space(1))) void*)g,
        (__attribute__((address_space(3))) void*)l, 16, 0, 0);
}

__device__ __forceinline__ float wave_sum(float v) {
    v += __shfl_down(v, 32);
    v += __shfl_down(v, 16);
    v += __shfl_down(v, 8);
    v += __shfl_down(v, 4);
    v += __shfl_down(v, 2);
    v += __shfl_down(v, 1);
    return v;
}

__device__ __forceinline__ float block_mean_256(float v, float* red, int tid) {
    float s = wave_sum(v);
    if ((tid & 63) == 0) red[tid >> 6] = s;
    __syncthreads();
    if (tid == 0) red[4] = (red[0] + red[1] + red[2] + red[3]) * (1.0f / 256.0f);
    __syncthreads();
    return red[4];
}

// fp32 -> bf16 cast
__global__ __launch_bounds__(256) void castw_kernel(
    const float* __restrict__ src, __hip_bfloat16* __restrict__ dst, int n)
{
    const int i = blockIdx.x * 256 + threadIdx.x;
    if (i < n) dst[i] = __float2bfloat16(src[i]);
}

// LN over C=256 fused with roll(-3,-3) + 7x7 window partition gather -> bf16.
__global__ __launch_bounds__(256) void ln1_window_kernel(
    const float* __restrict__ x1, const float* __restrict__ g,
    const float* __restrict__ b, __hip_bfloat16* __restrict__ out)
{
    __shared__ float red[8];
    const int t = blockIdx.x;
    const int c = threadIdx.x;
    const int bw = t / TPW, n = t - bw * TPW;
    const int bb = bw >> 8, wi = bw & 255;
    const int hb = wi >> 3, wb = wi & 7;
    const int i = n / 7, j = n - i * 7;
    int h0 = hb * 7 + i + 3; if (h0 >= GH) h0 -= GH;
    int w0 = wb * 7 + j + 3; if (w0 >= GW) w0 -= GW;
    const long src = ((long)(bb * GH + h0) * GW + w0) * CDIM + c;
    const float v = x1[src];
    const float mean = block_mean_256(v, red, c);
    const float d = v - mean;
    const float var = block_mean_256(d * d, red, c);
    out[(long)t * CDIM + c] = __float2bfloat16(d * rsqrtf(var + 1e-5f) * g[c] + b[c]);
}

// Plain LN over C=256 -> bf16.
__global__ __launch_bounds__(256) void ln_kernel(
    const float* __restrict__ x, const float* __restrict__ g,
    const float* __restrict__ b, __hip_bfloat16* __restrict__ out)
{
    __shared__ float red[8];
    const int t = blockIdx.x;
    const int c = threadIdx.x;
    const float v = x[(long)t * CDIM + c];
    const float mean = block_mean_256(v, red, c);
    const float d = v - mean;
    const float var = block_mean_256(d * d, red, c);
    out[(long)t * CDIM + c] = __float2bfloat16(d * rsqrtf(var + 1e-5f) * g[c] + b[c]);
}

// MFMA GEMM: Y[m,n] = sum_k X[m,k]*W[n,k] + bias[n]. X:(M,K) bf16, W:(N,K) bf16.
// 128x128 tile, BK=32, 256 threads = 4 waves, each wave 64x64 (4x4 of 16x16x32).
// EPI: 0 = bias only, 1 = bias+GELU, 2 = bias + fp32 residual (in-place safe).
// M % 128 == 0, N % 128 == 0, K % 32 == 0.
template <int EPI, typename OutT>
__global__ __launch_bounds__(256) void gemm_mfma(
    const __hip_bfloat16* __restrict__ X, const __hip_bfloat16* __restrict__ W,
    const float* __restrict__ bias, OutT* __restrict__ Y,
    int M, int K, int N, const float* __restrict__ res)
{
    __shared__ __hip_bfloat16 As[128 * 32];
    __shared__ __hip_bfloat16 Bs[128 * 32];
    const int tid = threadIdx.x;
    const int wave = tid >> 6, lane = tid & 63;
    const int bm = blockIdx.y * 128, bn = blockIdx.x * 128;
    const int wm = (wave & 1) * 64, wn = (wave >> 1) * 64;
    const int m16 = lane & 15, quad = lane >> 4;
    const int srow = lane >> 2;          // 0..15 (row within a 16-row group)
    const int scol = (lane & 3) * 8;     // bf16 element offset (16 B per lane)

    f32x4 acc[4][4] = {};

    const long xrow0 = (long)(bm + wave * 32) * K;   // wave stages rows [wave*32, wave*32+32)
    const long wrow0 = (long)(bn + wave * 32) * K;

    for (int k0 = 0; k0 < K; k0 += 32) {
#pragma unroll
        for (int j = 0; j < 2; ++j) {
            const int rg = wave * 2 + j;             // 16-row group id, 0..7
            const int row = rg * 16 + srow;
            async_copy16(X + (long)(bm + row) * K + k0 + scol, (char*)As + rg * 1024);
            async_copy16(W + (long)(bn + row) * K + k0 + scol, (char*)Bs + rg * 1024);
        }
        __syncthreads();
        bf16x8 af[4], bf[4];
#pragma unroll
        for (int i = 0; i < 4; ++i)
            af[i] = *(const bf16x8*)&As[(wm + i * 16 + m16) * 32 + quad * 8];
#pragma unroll
        for (int j = 0; j < 4; ++j)
            bf[j] = *(const bf16x8*)&Bs[(wn + j * 16 + m16) * 32 + quad * 8];
#pragma unroll
        for (int i = 0; i < 4; ++i)
#pragma unroll
            for (int j = 0; j < 4; ++j)
                acc[i][j] = __builtin_amdgcn_mfma_f32_16x16x32_bf16(af[i], bf[j], acc[i][j], 0, 0, 0);
        __syncthreads();
    }

#pragma unroll
    for (int j = 0; j < 4; ++j) {
        const int col = bn + wn + j * 16 + m16;
        const float bcol = bias[col];
#pragma unroll
        for (int i = 0; i < 4; ++i) {
#pragma unroll
            for (int r = 0; r < 4; ++r) {
                const long row = bm + wm + i * 16 + quad * 4 + r;
                float v = acc[i][j][r] + bcol;
                if (EPI == 1) v = 0.5f * v * (1.0f + erff(v * 0.70710678118654752f));
                if (EPI == 2) v += res[row * N + col];
                store_val(&Y[row * N + col], v);
            }
        }
    }
}

// One block per (window, head). qkv: bf16 (MTOK, 768), feature = s*256+h*32+d.
// Writes yout (MTOK, 256) bf16 at feature h*32+d (windowed token order).
__global__ __launch_bounds__(256) void attn_kernel(
    const __hip_bfloat16* __restrict__ qkv,
    const float* __restrict__ rpb,     // (169, 8)
    __hip_bfloat16* __restrict__ yout)
{
    __shared__ float qs[49][32], ks[49][32], vs[49][32];
    __shared__ float sc[49][49];
    const int blk = blockIdx.x;
    const int bw = blk >> 3;
    const int head = blk & 7;
    const int tid = threadIdx.x;
    const int wi = bw & 255;
    const int hb = wi >> 3, wb = wi & 7;

    const __hip_bfloat16* base = qkv + (long)bw * TPW * 768 + head * 32;
    for (int e = tid; e < 49 * 32; e += 256) {
        const int n = e >> 5, d = e & 31;
        const long o = (long)n * 768 + d;
        qs[n][d] = __bfloat162float(base[o]) * 0.17677669529663687f;
        ks[n][d] = __bfloat162float(base[o + 256]);
        vs[n][d] = __bfloat162float(base[o + 512]);
    }
    __syncthreads();

    for (int e = tid; e < 49 * 49; e += 256) {
        const int n = e / 49, m = e - n * 49;
        float acc = 0.0f;
#pragma unroll
        for (int dd = 0; dd < 32; dd += 4) {
            const float4 qa = *(const float4*)&qs[n][dd];
            const float4 ka = *(const float4*)&ks[m][dd];
            acc += qa.x * ka.x + qa.y * ka.y + qa.z * ka.z + qa.w * ka.w;
        }
        const int in_ = n / 7, jn = n - in_ * 7;
        const int im = m / 7, jm = m - im * 7;
        acc += rpb[((in_ - im + 6) * 13 + (jn - jm + 6)) * 8 + head];
        const int hn = hb * 7 + in_, wn = wb * 7 + jn;
        const int hm = hb * 7 + im, wm = wb * 7 + jm;
        const int rn = (hn < 217 ? 0 : (hn < 221 ? 3 : 6)) + (wn < 49 ? 0 : (wn < 53 ? 1 : 2));
        const int rm = (hm < 217 ? 0 : (hm < 221 ? 3 : 6)) + (wm < 49 ? 0 : (wm < 53 ? 1 : 2));
        if (rn != rm) acc -= 100.0f;
        sc[n][m] = acc;
    }
    __syncthreads();

    if (tid < 49) {
        float mx = -1e30f;
        for (int m = 0; m < 49; ++m) mx = fmaxf(mx, sc[tid][m]);
        float sum = 0.0f;
        for (int m = 0; m < 49; ++m) { const float e = __expf(sc[tid][m] - mx); sc[tid][m] = e; sum += e; }
        const float inv = 1.0f / sum;
        for (int m = 0; m < 49; ++m) sc[tid][m] *= inv;
    }
    __syncthreads();

    for (int e = tid; e < 49 * 8; e += 256) {
        const int n = e >> 3, d4 = (e & 7) << 2;
        float4 a = {0.f, 0.f, 0.f, 0.f};
        for (int m = 0; m < 49; ++m) {
            const float p = sc[n][m];
            const float4 vv = *(const float4*)&vs[m][d4];
            a.x += p * vv.x; a.y += p * vv.y; a.z += p * vv.z; a.w += p * vv.w;
        }
        const long o = ((long)bw * TPW + n) * CDIM + head * 32 + d4;
        short4 pk;
        { __hip_bfloat16 h = __float2bfloat16(a.x); pk.x = *(short*)&h; }
        { __hip_bfloat16 h = __float2bfloat16(a.y); pk.y = *(short*)&h; }
        { __hip_bfloat16 h = __float2bfloat16(a.z); pk.z = *(short*)&h; }
        { __hip_bfloat16 h = __float2bfloat16(a.w); pk.w = *(short*)&h; }
        *(short4*)((short*)yout + o) = pk;
    }
}

// Window-reverse + roll(+3,+3) scatter; writes out2 (attn branch output, fp32)
// and x1b = x1 + y (fp32, goes straight into out_x1).
__global__ __launch_bounds__(256) void scatter_kernel(
    const float* __restrict__ yproj, const float* __restrict__ x1,
    float* __restrict__ out2, float* __restrict__ x1b)
{
    const int t = blockIdx.x;
    const int c = threadIdx.x;
    const int bw = t / TPW, n = t - bw * TPW;
    const int bb = bw >> 8, wi = bw & 255;
    const int hb = wi >> 3, wb = wi & 7;
    const int i = n / 7, j = n - i * 7;
    int h0 = hb * 7 + i + 3; if (h0 >= GH) h0 -= GH;
    int w0 = wb * 7 + j + 3; if (w0 >= GW) w0 -= GW;
    const long dst = ((long)bb * (GH * GW) + h0 * GW + w0) * CDIM + c;
    const float y = yproj[(long)t * CDIM + c];
    out2[dst] = y;
    x1b[dst] = x1[dst] + y;
}

extern "C" void kernel_launch(void* const* d_in, const int* in_sizes, int n_in,
                              void* d_out, int out_size, void* d_ws, size_t ws_size,
                              hipStream_t stream) {
    (void)in_sizes; (void)n_in; (void)out_size; (void)ws_size;
    const float* x1     = (const float*)d_in[0];
    const float* n1g    = (const float*)d_in[2];
    const float* n1b    = (const float*)d_in[3];
    const float* qkv_w  = (const float*)d_in[4];
    const float* qkv_b  = (const float*)d_in[5];
    const float* proj_w = (const float*)d_in[6];
    const float* proj_b = (const float*)d_in[7];
    const float* rpb    = (const float*)d_in[8];
    const float* n2g    = (const float*)d_in[9];
    const float* n2b    = (const float*)d_in[10];
    const float* fc1_w  = (const float*)d_in[11];
    const float* fc1_b  = (const float*)d_in[12];
    const float* fc2_w  = (const float*)d_in[13];
    const float* fc2_b  = (const float*)d_in[14];

    float* out_x1 = (float*)d_out;                       // output 0: x1_new (also x1b staging)
    float* out_y  = out_x1 + (long)MTOK * CDIM;          // output 1: attn branch

    char* ws = (char*)d_ws;
    const size_t SZ_A   = (size_t)MTOK * CDIM * sizeof(__hip_bfloat16);   // 25.7 MB
    const size_t SZ_BIG = (size_t)MTOK * 1024 * sizeof(__hip_bfloat16);   // 102.8 MB
    __hip_bfloat16* A    = (__hip_bfloat16*)ws;            // ln1 out -> yattn -> ln2 out
    char*           BIG  = ws + SZ_A;                      // qkv bf16 -> proj fp32 -> h1 bf16
    __hip_bfloat16* qkvb = (__hip_bfloat16*)BIG;
    float*          P    = (float*)BIG;
    __hip_bfloat16* H1   = (__hip_bfloat16*)BIG;
    __hip_bfloat16* wB   = (__hip_bfloat16*)(ws + SZ_A + SZ_BIG);         // bf16 weights
    __hip_bfloat16* qkv_wb  = wB;               // 196608
    __hip_bfloat16* proj_wb = wB + 196608;      // 65536
    __hip_bfloat16* fc1_wb  = wB + 262144;      // 262144
    __hip_bfloat16* fc2_wb  = wB + 524288;      // 262144

    // 0) weights -> bf16
    castw_kernel<<<768, 256, 0, stream>>>(qkv_w, qkv_wb, 196608);
    castw_kernel<<<256, 256, 0, stream>>>(proj_w, proj_wb, 65536);
    castw_kernel<<<1024, 256, 0, stream>>>(fc1_w, fc1_wb, 262144);
    castw_kernel<<<1024, 256, 0, stream>>>(fc2_w, fc2_wb, 262144);
    // 1) LN1 + roll + window partition (bf16)
    ln1_window_kernel<<<MTOK, 256, 0, stream>>>(x1, n1g, n1b, A);
    // 2) QKV gemm (bf16 MFMA) -> bf16
    gemm_mfma<0, __hip_bfloat16><<<dim3(768 / 128, MTOK / 128), 256, 0, stream>>>(
        A, qkv_wb, qkv_b, qkvb, MTOK, CDIM, 768, nullptr);
    // 3) windowed attention -> bf16 (into A)
    attn_kernel<<<NWIN * NHEAD, 256, 0, stream>>>(qkvb, rpb, A);
    // 4) proj (bf16 MFMA) -> fp32
    gemm_mfma<0, float><<<dim3(256 / 128, MTOK / 128), 256, 0, stream>>>(
        A, proj_wb, proj_b, P, MTOK, CDIM, CDIM, nullptr);
    // 5) reverse windows + unshift; writes out_y and x1b (into out_x1)
    scatter_kernel<<<MTOK, 256, 0, stream>>>(P, x1, out_y, out_x1);
    // 6) LN2 -> bf16 (into A)
    ln_kernel<<<MTOK, 256, 0, stream>>>(out_x1, n2g, n2b, A);
    // 7) fc1 + GELU -> bf16
    gemm_mfma<1, __hip_bfloat16><<<dim3(1024 / 128, MTOK / 128), 256, 0, stream>>>(
        A, fc1_wb, fc1_b, H1, MTOK, CDIM, 1024, nullptr);
    // 8) fc2 + residual (in-place on out_x1)
    gemm_mfma<2, float><<<dim3(256 / 128, MTOK / 128), 256, 0, stream>>>(
        H1, fc2_wb, fc2_b, out_x1, MTOK, 1024, CDIM, out_x1);
}

// Round 3
// 554.831 us; speedup vs baseline: 3.1306x; 1.2329x over previous
//
#include <hip/hip_runtime.h>
#include <hip/hip_bf16.h>
#include <cmath>

#define CDIM 256
#define TPW 49
#define NWIN 1024
#define MTOK (NWIN * TPW)   // 50176 tokens (windowed order)
#define NHEAD 8
#define GH 224
#define GW 56
#define PLD 72              // padded LDS row (bf16 elems): 144 B, 16B-aligned, 2-way banks

typedef __attribute__((ext_vector_type(8))) __bf16 bf16x8;
typedef __attribute__((ext_vector_type(4))) float f32x4;

__device__ __forceinline__ void store_val(float* p, float v) { *p = v; }
__device__ __forceinline__ void store_val(__hip_bfloat16* p, float v) { *p = __float2bfloat16(v); }

__device__ __forceinline__ __bf16 to_bf16(float f) {
    __hip_bfloat16 h = __float2bfloat16(f);
    return *(__bf16*)&h;
}

__device__ __forceinline__ void async_copy16(const void* g, void* l) {
    __builtin_amdgcn_global_load_lds(
        (const __attribute__((address_space(1))) void*)g,
        (__attribute__((address_space(3))) void*)l, 16, 0, 0);
}

__device__ __forceinline__ float wave_sum(float v) {
    v += __shfl_down(v, 32);
    v += __shfl_down(v, 16);
    v += __shfl_down(v, 8);
    v += __shfl_down(v, 4);
    v += __shfl_down(v, 2);
    v += __shfl_down(v, 1);
    return v;
}

__device__ __forceinline__ float block_mean_256(float v, float* red, int tid) {
    float s = wave_sum(v);
    if ((tid & 63) == 0) red[tid >> 6] = s;
    __syncthreads();
    if (tid == 0) red[4] = (red[0] + red[1] + red[2] + red[3]) * (1.0f / 256.0f);
    __syncthreads();
    return red[4];
}

// fp32 -> bf16 cast
__global__ __launch_bounds__(256) void castw_kernel(
    const float* __restrict__ src, __hip_bfloat16* __restrict__ dst, int n)
{
    const int i = blockIdx.x * 256 + threadIdx.x;
    if (i < n) dst[i] = __float2bfloat16(src[i]);
}

// Combined rel-pos bias + shift mask, transposed: cbt[cls*8+head][m][n] (64x64).
// cls = (hb==31)*2 + (wb==7). Padded entries (m>=49 or n>=49) = -30000.
__global__ __launch_bounds__(256) void cb_kernel(
    const float* __restrict__ rpb, float* __restrict__ cbt)
{
    const int cls = blockIdx.x >> 3, head = blockIdx.x & 7;
    for (int e = threadIdx.x; e < 64 * 64; e += 256) {
        const int m = e >> 6, n = e & 63;
        float v;
        if (m >= 49 || n >= 49) v = -30000.0f;
        else {
            const int in_ = n / 7, jn = n - in_ * 7;
            const int im = m / 7, jm = m - im * 7;
            v = rpb[((in_ - im + 6) * 13 + (jn - jm + 6)) * 8 + head];
            const int hn = (cls & 2) ? 217 + in_ : in_;
            const int wn = (cls & 1) ? 49 + jn : jn;
            const int hm = (cls & 2) ? 217 + im : im;
            const int wm = (cls & 1) ? 49 + jm : jm;
            const int rn = (hn < 217 ? 0 : (hn < 221 ? 3 : 6)) + (wn < 49 ? 0 : (wn < 53 ? 1 : 2));
            const int rm = (hm < 217 ? 0 : (hm < 221 ? 3 : 6)) + (wm < 49 ? 0 : (wm < 53 ? 1 : 2));
            if (rn != rm) v -= 100.0f;
        }
        cbt[((long)blockIdx.x * 64 + m) * 64 + n] = v;
    }
}

// LN over C=256 fused with roll(-3,-3) + 7x7 window partition gather -> bf16.
__global__ __launch_bounds__(256) void ln1_window_kernel(
    const float* __restrict__ x1, const float* __restrict__ g,
    const float* __restrict__ b, __hip_bfloat16* __restrict__ out)
{
    __shared__ float red[8];
    const int t = blockIdx.x;
    const int c = threadIdx.x;
    const int bw = t / TPW, n = t - bw * TPW;
    const int bb = bw >> 8, wi = bw & 255;
    const int hb = wi >> 3, wb = wi & 7;
    const int i = n / 7, j = n - i * 7;
    int h0 = hb * 7 + i + 3; if (h0 >= GH) h0 -= GH;
    int w0 = wb * 7 + j + 3; if (w0 >= GW) w0 -= GW;
    const long src = ((long)(bb * GH + h0) * GW + w0) * CDIM + c;
    const float v = x1[src];
    const float mean = block_mean_256(v, red, c);
    const float d = v - mean;
    const float var = block_mean_256(d * d, red, c);
    out[(long)t * CDIM + c] = __float2bfloat16(d * rsqrtf(var + 1e-5f) * g[c] + b[c]);
}

// Plain LN over C=256 -> bf16.
__global__ __launch_bounds__(256) void ln_kernel(
    const float* __restrict__ x, const float* __restrict__ g,
    const float* __restrict__ b, __hip_bfloat16* __restrict__ out)
{
    __shared__ float red[8];
    const int t = blockIdx.x;
    const int c = threadIdx.x;
    const float v = x[(long)t * CDIM + c];
    const float mean = block_mean_256(v, red, c);
    const float d = v - mean;
    const float var = block_mean_256(d * d, red, c);
    out[(long)t * CDIM + c] = __float2bfloat16(d * rsqrtf(var + 1e-5f) * g[c] + b[c]);
}

// MFMA GEMM: Y[m,n] = sum_k X[m,k]*W[n,k] + bias[n]. X:(M,K) bf16, W:(N,K) bf16.
// 128x128 tile, BK=32, 256 threads = 4 waves, each wave 64x64 (4x4 of 16x16x32).
// EPI: 0 = bias only, 1 = bias+GELU, 2 = bias + fp32 residual (in-place safe).
template <int EPI, typename OutT>
__global__ __launch_bounds__(256) void gemm_mfma(
    const __hip_bfloat16* __restrict__ X, const __hip_bfloat16* __restrict__ W,
    const float* __restrict__ bias, OutT* __restrict__ Y,
    int M, int K, int N, const float* __restrict__ res)
{
    __shared__ __hip_bfloat16 As[128 * 32];
    __shared__ __hip_bfloat16 Bs[128 * 32];
    const int tid = threadIdx.x;
    const int wave = tid >> 6, lane = tid & 63;
    const int bm = blockIdx.y * 128, bn = blockIdx.x * 128;
    const int wm = (wave & 1) * 64, wn = (wave >> 1) * 64;
    const int m16 = lane & 15, quad = lane >> 4;
    const int srow = lane >> 2;
    const int scol = (lane & 3) * 8;

    f32x4 acc[4][4] = {};

    for (int k0 = 0; k0 < K; k0 += 32) {
#pragma unroll
        for (int j = 0; j < 2; ++j) {
            const int rg = wave * 2 + j;
            const int row = rg * 16 + srow;
            async_copy16(X + (long)(bm + row) * K + k0 + scol, (char*)As + rg * 1024);
            async_copy16(W + (long)(bn + row) * K + k0 + scol, (char*)Bs + rg * 1024);
        }
        __syncthreads();
        bf16x8 af[4], bf[4];
#pragma unroll
        for (int i = 0; i < 4; ++i)
            af[i] = *(const bf16x8*)&As[(wm + i * 16 + m16) * 32 + quad * 8];
#pragma unroll
        for (int j = 0; j < 4; ++j)
            bf[j] = *(const bf16x8*)&Bs[(wn + j * 16 + m16) * 32 + quad * 8];
#pragma unroll
        for (int i = 0; i < 4; ++i)
#pragma unroll
            for (int j = 0; j < 4; ++j)
                acc[i][j] = __builtin_amdgcn_mfma_f32_16x16x32_bf16(af[i], bf[j], acc[i][j], 0, 0, 0);
        __syncthreads();
    }

#pragma unroll
    for (int j = 0; j < 4; ++j) {
        const int col = bn + wn + j * 16 + m16;
        const float bcol = bias[col];
#pragma unroll
        for (int i = 0; i < 4; ++i) {
#pragma unroll
            for (int r = 0; r < 4; ++r) {
                const long row = bm + wm + i * 16 + quad * 4 + r;
                float v = acc[i][j][r] + bcol;
                if (EPI == 1) v = 0.5f * v * (1.0f + erff(v * 0.70710678118654752f));
                if (EPI == 2) v += res[row * N + col];
                store_val(&Y[row * N + col], v);
            }
        }
    }
}

// MFMA attention: one wave per (window, head); block = 4 waves = 4 heads.
// grid = NWIN*2; bw = blockIdx>>1, heads (blockIdx&1)*4 + wave.
// qkv: bf16 (MTOK, 768) feature = s*256 + h*32 + d. yout: bf16 (MTOK, 256).
__global__ __launch_bounds__(256) void attn_mfma_kernel(
    const __hip_bfloat16* __restrict__ qkv,
    const float* __restrict__ cbt,
    __hip_bfloat16* __restrict__ yout)
{
    __shared__ __bf16 P[4][64][PLD];
    const int tid = threadIdx.x;
    const int wave = tid >> 6, lane = tid & 63;
    const int bw = blockIdx.x >> 1;
    const int head = (blockIdx.x & 1) * 4 + wave;
    const int m16 = lane & 15, quad = lane >> 4;
    const int wi = bw & 255;
    const int hb = wi >> 3, wb = wi & 7;
    const int cls = ((hb == 31) ? 2 : 0) + ((wb == 7) ? 1 : 0);

    const __bf16* qb = (const __bf16*)qkv + (long)bw * TPW * 768 + head * 32;

    // Q (A-op) and K (B-op) fragments straight from global; rows >=49 zero.
    bf16x8 qf[4], kf[4];
#pragma unroll
    for (int i = 0; i < 4; ++i) {
        const int n = i * 16 + m16;
        bf16x8 q = {}, k = {};
        if (n < TPW) {
            const __bf16* p = qb + (long)n * 768 + quad * 8;
            q = *(const bf16x8*)p;
            k = *(const bf16x8*)(p + 256);
        }
        qf[i] = q; kf[i] = k;
    }

    // V fragments (B-op for PV): vf[jt][kt], lane holds V[tok=kt*32+quad*8+j][d=jt*16+m16]
    bf16x8 vf[2][2];
#pragma unroll
    for (int jt = 0; jt < 2; ++jt)
#pragma unroll
        for (int kt = 0; kt < 2; ++kt) {
            bf16x8 v = {};
#pragma unroll
            for (int j = 0; j < 8; ++j) {
                const int tok = kt * 32 + quad * 8 + j;
                if (tok < TPW) v[j] = qb[(long)tok * 768 + 512 + jt * 16 + m16];
            }
            vf[jt][kt] = v;
        }

    // S = Q K^T  (C-layout: lane holds S[n=i*16+quad*4+r][m=j*16+m16])
    f32x4 s[4][4] = {};
#pragma unroll
    for (int i = 0; i < 4; ++i)
#pragma unroll
        for (int j = 0; j < 4; ++j)
            s[i][j] = __builtin_amdgcn_mfma_f32_16x16x32_bf16(qf[i], kf[j], s[i][j], 0, 0, 0);

    // scale + combined bias/mask
    const float* cb = cbt + (long)(cls * 8 + head) * 64 * 64;   // [m][n]
#pragma unroll
    for (int j = 0; j < 4; ++j) {
        const int m = j * 16 + m16;
#pragma unroll
        for (int i = 0; i < 4; ++i) {
            const float4 c = *(const float4*)(cb + m * 64 + i * 16 + quad * 4);
            s[i][j][0] = s[i][j][0] * 0.17677669529663687f + c.x;
            s[i][j][1] = s[i][j][1] * 0.17677669529663687f + c.y;
            s[i][j][2] = s[i][j][2] * 0.17677669529663687f + c.z;
            s[i][j][3] = s[i][j][3] * 0.17677669529663687f + c.w;
        }
    }

    // row softmax (rows live in 16 lanes sharing quad)
    float inv[4][4];
#pragma unroll
    for (int i = 0; i < 4; ++i) {
#pragma unroll
        for (int r = 0; r < 4; ++r) {
            float mx = fmaxf(fmaxf(s[i][0][r], s[i][1][r]), fmaxf(s[i][2][r], s[i][3][r]));
            mx = fmaxf(mx, __shfl_xor(mx, 1));
            mx = fmaxf(mx, __shfl_xor(mx, 2));
            mx = fmaxf(mx, __shfl_xor(mx, 4));
            mx = fmaxf(mx, __shfl_xor(mx, 8));
            float sum = 0.0f;
#pragma unroll
            for (int j = 0; j < 4; ++j) {
                const float e = __expf(s[i][j][r] - mx);
                s[i][j][r] = e;
                sum += e;
            }
            sum += __shfl_xor(sum, 1);
            sum += __shfl_xor(sum, 2);
            sum += __shfl_xor(sum, 4);
            sum += __shfl_xor(sum, 8);
            inv[i][r] = 1.0f / sum;
        }
    }

    // unnormalized P -> LDS (per-wave tile, no cross-wave barrier needed)
#pragma unroll
    for (int i = 0; i < 4; ++i)
#pragma unroll
        for (int j = 0; j < 4; ++j)
#pragma unroll
            for (int r = 0; r < 4; ++r)
                P[wave][i * 16 + quad * 4 + r][j * 16 + m16] = to_bf16(s[i][j][r]);

    // O = P V  (A-frags from LDS, b128 16B-aligned)
    f32x4 o[4][2] = {};
#pragma unroll
    for (int kt = 0; kt < 2; ++kt)
#pragma unroll
        for (int i = 0; i < 4; ++i) {
            const bf16x8 pf = *(const bf16x8*)&P[wave][i * 16 + m16][kt * 32 + quad * 8];
#pragma unroll
            for (int jt = 0; jt < 2; ++jt)
                o[i][jt] = __builtin_amdgcn_mfma_f32_16x16x32_bf16(pf, vf[jt][kt], o[i][jt], 0, 0, 0);
        }

    // normalize + store rows n < 49
#pragma unroll
    for (int i = 0; i < 4; ++i)
#pragma unroll
        for (int r = 0; r < 4; ++r) {
            const int n = i * 16 + quad * 4 + r;
            if (n < TPW) {
                const float sc_ = inv[i][r];
                __bf16* yp = (__bf16*)yout + ((long)bw * TPW + n) * CDIM + head * 32;
                yp[m16] = to_bf16(o[i][0][r] * sc_);
                yp[16 + m16] = to_bf16(o[i][1][r] * sc_);
            }
        }
}

// Window-reverse + roll(+3,+3) scatter; writes out2 and x1b = x1 + y.
__global__ __launch_bounds__(256) void scatter_kernel(
    const float* __restrict__ yproj, const float* __restrict__ x1,
    float* __restrict__ out2, float* __restrict__ x1b)
{
    const int t = blockIdx.x;
    const int c = threadIdx.x;
    const int bw = t / TPW, n = t - bw * TPW;
    const int bb = bw >> 8, wi = bw & 255;
    const int hb = wi >> 3, wb = wi & 7;
    const int i = n / 7, j = n - i * 7;
    int h0 = hb * 7 + i + 3; if (h0 >= GH) h0 -= GH;
    int w0 = wb * 7 + j + 3; if (w0 >= GW) w0 -= GW;
    const long dst = ((long)bb * (GH * GW) + h0 * GW + w0) * CDIM + c;
    const float y = yproj[(long)t * CDIM + c];
    out2[dst] = y;
    x1b[dst] = x1[dst] + y;
}

extern "C" void kernel_launch(void* const* d_in, const int* in_sizes, int n_in,
                              void* d_out, int out_size, void* d_ws, size_t ws_size,
                              hipStream_t stream) {
    (void)in_sizes; (void)n_in; (void)out_size; (void)ws_size;
    const float* x1     = (const float*)d_in[0];
    const float* n1g    = (const float*)d_in[2];
    const float* n1b    = (const float*)d_in[3];
    const float* qkv_w  = (const float*)d_in[4];
    const float* qkv_b  = (const float*)d_in[5];
    const float* proj_w = (const float*)d_in[6];
    const float* proj_b = (const float*)d_in[7];
    const float* rpb    = (const float*)d_in[8];
    const float* n2g    = (const float*)d_in[9];
    const float* n2b    = (const float*)d_in[10];
    const float* fc1_w  = (const float*)d_in[11];
    const float* fc1_b  = (const float*)d_in[12];
    const float* fc2_w  = (const float*)d_in[13];
    const float* fc2_b  = (const float*)d_in[14];

    float* out_x1 = (float*)d_out;
    float* out_y  = out_x1 + (long)MTOK * CDIM;

    char* ws = (char*)d_ws;
    const size_t SZ_A   = (size_t)MTOK * CDIM * sizeof(__hip_bfloat16);   // 25.7 MB
    const size_t SZ_BIG = (size_t)MTOK * 1024 * sizeof(__hip_bfloat16);   // 102.8 MB
    __hip_bfloat16* A    = (__hip_bfloat16*)ws;            // ln1 out -> yattn -> ln2 out
    char*           BIG  = ws + SZ_A;                      // qkv bf16 -> proj fp32 -> h1 bf16
    __hip_bfloat16* qkvb = (__hip_bfloat16*)BIG;
    float*          P    = (float*)BIG;
    __hip_bfloat16* H1   = (__hip_bfloat16*)BIG;
    __hip_bfloat16* wB   = (__hip_bfloat16*)(ws + SZ_A + SZ_BIG);
    __hip_bfloat16* qkv_wb  = wB;               // 196608
    __hip_bfloat16* proj_wb = wB + 196608;      // 65536
    __hip_bfloat16* fc1_wb  = wB + 262144;      // 262144
    __hip_bfloat16* fc2_wb  = wB + 524288;      // 262144
    float* cbt = (float*)(wB + 786432);         // 4*8*64*64 fp32 = 512 KB

    // 0) weights -> bf16; combined bias/mask table
    castw_kernel<<<768, 256, 0, stream>>>(qkv_w, qkv_wb, 196608);
    castw_kernel<<<256, 256, 0, stream>>>(proj_w, proj_wb, 65536);
    castw_kernel<<<1024, 256, 0, stream>>>(fc1_w, fc1_wb, 262144);
    castw_kernel<<<1024, 256, 0, stream>>>(fc2_w, fc2_wb, 262144);
    cb_kernel<<<32, 256, 0, stream>>>(rpb, cbt);
    // 1) LN1 + roll + window partition (bf16)
    ln1_window_kernel<<<MTOK, 256, 0, stream>>>(x1, n1g, n1b, A);
    // 2) QKV gemm (bf16 MFMA) -> bf16
    gemm_mfma<0, __hip_bfloat16><<<dim3(768 / 128, MTOK / 128), 256, 0, stream>>>(
        A, qkv_wb, qkv_b, qkvb, MTOK, CDIM, 768, nullptr);
    // 3) windowed attention (MFMA) -> bf16 (into A)
    attn_mfma_kernel<<<NWIN * 2, 256, 0, stream>>>(qkvb, cbt, A);
    // 4) proj (bf16 MFMA) -> fp32
    gemm_mfma<0, float><<<dim3(256 / 128, MTOK / 128), 256, 0, stream>>>(
        A, proj_wb, proj_b, P, MTOK, CDIM, CDIM, nullptr);
    // 5) reverse windows + unshift; writes out_y and x1b (into out_x1)
    scatter_kernel<<<MTOK, 256, 0, stream>>>(P, x1, out_y, out_x1);
    // 6) LN2 -> bf16 (into A)
    ln_kernel<<<MTOK, 256, 0, stream>>>(out_x1, n2g, n2b, A);
    // 7) fc1 + GELU -> bf16
    gemm_mfma<1, __hip_bfloat16><<<dim3(1024 / 128, MTOK / 128), 256, 0, stream>>>(
        A, fc1_wb, fc1_b, H1, MTOK, CDIM, 1024, nullptr);
    // 8) fc2 + residual (in-place on out_x1)
    gemm_mfma<2, float><<<dim3(256 / 128, MTOK / 128), 256, 0, stream>>>(
        H1, fc2_wb, fc2_b, out_x1, MTOK, 1024, CDIM, out_x1);
}

// Round 4
// 527.100 us; speedup vs baseline: 3.2953x; 1.0526x over previous
//
#include <hip/hip_runtime.h>
#include <hip/hip_bf16.h>
#include <cmath>

#define CDIM 256
#define TPW 49
#define NWIN 1024
#define MTOK (NWIN * TPW)   // 50176 tokens (windowed order)
#define NHEAD 8
#define GH 224
#define GW 56
#define PLD 72              // padded LDS row (bf16 elems)

typedef __attribute__((ext_vector_type(8))) __bf16 bf16x8;
typedef __attribute__((ext_vector_type(4))) float f32x4;

__device__ __forceinline__ __bf16 to_bf16(float f) {
    __hip_bfloat16 h = __float2bfloat16(f);
    return *(__bf16*)&h;
}

__device__ __forceinline__ void async_copy16(const void* g, void* l) {
    __builtin_amdgcn_global_load_lds(
        (const __attribute__((address_space(1))) void*)g,
        (__attribute__((address_space(3))) void*)l, 16, 0, 0);
}

__device__ __forceinline__ float wave_sum(float v) {
    v += __shfl_down(v, 32);
    v += __shfl_down(v, 16);
    v += __shfl_down(v, 8);
    v += __shfl_down(v, 4);
    v += __shfl_down(v, 2);
    v += __shfl_down(v, 1);
    return v;
}

__device__ __forceinline__ float block_mean_256(float v, float* red, int tid) {
    float s = wave_sum(v);
    if ((tid & 63) == 0) red[tid >> 6] = s;
    __syncthreads();
    if (tid == 0) red[4] = (red[0] + red[1] + red[2] + red[3]) * (1.0f / 256.0f);
    __syncthreads();
    return red[4];
}

// all four weight tensors -> bf16, one launch
__global__ __launch_bounds__(256) void castall_kernel(
    const float* __restrict__ qw, const float* __restrict__ pw,
    const float* __restrict__ f1, const float* __restrict__ f2,
    __hip_bfloat16* __restrict__ dst)
{
    const int i = blockIdx.x * 256 + threadIdx.x;
    float v;
    if (i < 196608) v = qw[i];
    else if (i < 262144) v = pw[i - 196608];
    else if (i < 524288) v = f1[i - 262144];
    else v = f2[i - 524288];
    dst[i] = __float2bfloat16(v);
}

// Combined rel-pos bias + shift mask, transposed: cbt[cls*8+head][m][n] (64x64).
__global__ __launch_bounds__(256) void cb_kernel(
    const float* __restrict__ rpb, float* __restrict__ cbt)
{
    const int cls = blockIdx.x >> 3, head = blockIdx.x & 7;
    for (int e = threadIdx.x; e < 64 * 64; e += 256) {
        const int m = e >> 6, n = e & 63;
        float v;
        if (m >= 49 || n >= 49) v = -30000.0f;
        else {
            const int in_ = n / 7, jn = n - in_ * 7;
            const int im = m / 7, jm = m - im * 7;
            v = rpb[((in_ - im + 6) * 13 + (jn - jm + 6)) * 8 + head];
            const int hn = (cls & 2) ? 217 + in_ : in_;
            const int wn = (cls & 1) ? 49 + jn : jn;
            const int hm = (cls & 2) ? 217 + im : im;
            const int wm = (cls & 1) ? 49 + jm : jm;
            const int rn = (hn < 217 ? 0 : (hn < 221 ? 3 : 6)) + (wn < 49 ? 0 : (wn < 53 ? 1 : 2));
            const int rm = (hm < 217 ? 0 : (hm < 221 ? 3 : 6)) + (wm < 49 ? 0 : (wm < 53 ? 1 : 2));
            if (rn != rm) v -= 100.0f;
        }
        cbt[((long)blockIdx.x * 64 + m) * 64 + n] = v;
    }
}

// LN over C=256 fused with roll(-3,-3) + 7x7 window partition gather -> bf16.
__global__ __launch_bounds__(256) void ln1_window_kernel(
    const float* __restrict__ x1, const float* __restrict__ g,
    const float* __restrict__ b, __hip_bfloat16* __restrict__ out)
{
    __shared__ float red[8];
    const int t = blockIdx.x;
    const int c = threadIdx.x;
    const int bw = t / TPW, n = t - bw * TPW;
    const int bb = bw >> 8, wi = bw & 255;
    const int hb = wi >> 3, wb = wi & 7;
    const int i = n / 7, j = n - i * 7;
    int h0 = hb * 7 + i + 3; if (h0 >= GH) h0 -= GH;
    int w0 = wb * 7 + j + 3; if (w0 >= GW) w0 -= GW;
    const long src = ((long)(bb * GH + h0) * GW + w0) * CDIM + c;
    const float v = x1[src];
    const float mean = block_mean_256(v, red, c);
    const float d = v - mean;
    const float var = block_mean_256(d * d, red, c);
    out[(long)t * CDIM + c] = __float2bfloat16(d * rsqrtf(var + 1e-5f) * g[c] + b[c]);
}

// Plain LN over C=256 -> bf16.
__global__ __launch_bounds__(256) void ln_kernel(
    const float* __restrict__ x, const float* __restrict__ g,
    const float* __restrict__ b, __hip_bfloat16* __restrict__ out)
{
    __shared__ float red[8];
    const int t = blockIdx.x;
    const int c = threadIdx.x;
    const float v = x[(long)t * CDIM + c];
    const float mean = block_mean_256(v, red, c);
    const float d = v - mean;
    const float var = block_mean_256(d * d, red, c);
    out[(long)t * CDIM + c] = __float2bfloat16(d * rsqrtf(var + 1e-5f) * g[c] + b[c]);
}

// MFMA GEMM: Y[m,n] = sum_k X[m,k]*W[n,k] + bias[n]. X:(M,K) bf16, W:(N,K) bf16.
// 128x128 tile, BK=32, 256 threads = 4 waves. Operand-swapped MFMA: lane owns
// row m = i*16+m16, cols n = j*16+quad*4+[0,4) -> wide contiguous stores.
// EPI: 0 = bias (bf16 out), 1 = bias+GELU (bf16 out), 2 = bias + fp32 residual
// (fp32 out, in-place safe), 3 = proj+scatter: Y=x1b (fp32), Y2=out_y, res=x1.
template <int EPI, typename OutT>
__global__ __launch_bounds__(256) void gemm_mfma(
    const __hip_bfloat16* __restrict__ X, const __hip_bfloat16* __restrict__ W,
    const float* __restrict__ bias, OutT* __restrict__ Y,
    int M, int K, int N, const float* __restrict__ res, float* __restrict__ Y2)
{
    __shared__ __hip_bfloat16 As[128 * 32];
    __shared__ __hip_bfloat16 Bs[128 * 32];
    const int tid = threadIdx.x;
    const int wave = tid >> 6, lane = tid & 63;
    const int bm = blockIdx.y * 128, bn = blockIdx.x * 128;
    const int wm = (wave & 1) * 64, wn = (wave >> 1) * 64;
    const int m16 = lane & 15, quad = lane >> 4;
    const int srow = lane >> 2;
    const int scol = (lane & 3) * 8;

    f32x4 acc[4][4] = {};

    for (int k0 = 0; k0 < K; k0 += 32) {
#pragma unroll
        for (int j = 0; j < 2; ++j) {
            const int rg = wave * 2 + j;
            const int row = rg * 16 + srow;
            async_copy16(X + (long)(bm + row) * K + k0 + scol, (char*)As + rg * 1024);
            async_copy16(W + (long)(bn + row) * K + k0 + scol, (char*)Bs + rg * 1024);
        }
        __syncthreads();
        bf16x8 af[4], bf[4];
#pragma unroll
        for (int i = 0; i < 4; ++i)
            af[i] = *(const bf16x8*)&As[(wm + i * 16 + m16) * 32 + quad * 8];
#pragma unroll
        for (int j = 0; j < 4; ++j)
            bf[j] = *(const bf16x8*)&Bs[(wn + j * 16 + m16) * 32 + quad * 8];
        // swapped operands: D = C^T layout -> lane owns 4 consecutive cols
#pragma unroll
        for (int i = 0; i < 4; ++i)
#pragma unroll
            for (int j = 0; j < 4; ++j)
                acc[i][j] = __builtin_amdgcn_mfma_f32_16x16x32_bf16(bf[j], af[i], acc[i][j], 0, 0, 0);
        __syncthreads();
    }

#pragma unroll
    for (int i = 0; i < 4; ++i) {
        const long row = bm + wm + i * 16 + m16;
        long drow = row;
        if (EPI == 3) {
            const unsigned t = (unsigned)row;
            const unsigned bw_ = t / 49u;
            const unsigned n_ = t - bw_ * 49u;
            const unsigned bb = bw_ >> 8, wi = bw_ & 255u;
            const unsigned hb = wi >> 3, wbl = wi & 7u;
            const unsigned ii = n_ / 7u, jj = n_ - ii * 7u;
            int h0 = hb * 7 + ii + 3; if (h0 >= GH) h0 -= GH;
            int w0 = wbl * 7 + jj + 3; if (w0 >= GW) w0 -= GW;
            drow = (long)bb * (GH * GW) + h0 * GW + w0;
        }
#pragma unroll
        for (int j = 0; j < 4; ++j) {
            const int col = bn + wn + j * 16 + quad * 4;
            const float4 b4 = *(const float4*)&bias[col];
            float v[4];
            v[0] = acc[i][j][0] + b4.x;
            v[1] = acc[i][j][1] + b4.y;
            v[2] = acc[i][j][2] + b4.z;
            v[3] = acc[i][j][3] + b4.w;
            if (EPI == 1) {
#pragma unroll
                for (int r = 0; r < 4; ++r)
                    v[r] = 0.5f * v[r] * (1.0f + erff(v[r] * 0.70710678118654752f));
            }
            if (EPI == 0 || EPI == 1) {
                short4 pk;
                { __bf16 h = to_bf16(v[0]); pk.x = *(short*)&h; }
                { __bf16 h = to_bf16(v[1]); pk.y = *(short*)&h; }
                { __bf16 h = to_bf16(v[2]); pk.z = *(short*)&h; }
                { __bf16 h = to_bf16(v[3]); pk.w = *(short*)&h; }
                *(short4*)((short*)Y + row * N + col) = pk;
            } else if (EPI == 2) {
                const float4 r4 = *(const float4*)(res + row * N + col);
                float4 o4 = { v[0] + r4.x, v[1] + r4.y, v[2] + r4.z, v[3] + r4.w };
                *(float4*)((float*)Y + row * N + col) = o4;
            } else if (EPI == 3) {
                const long a = drow * 256 + col;
                const float4 x4 = *(const float4*)(res + a);
                float4 y4 = { v[0], v[1], v[2], v[3] };
                *(float4*)(Y2 + a) = y4;
                float4 s4 = { v[0] + x4.x, v[1] + x4.y, v[2] + x4.z, v[3] + x4.w };
                *(float4*)((float*)Y + a) = s4;
            }
        }
    }
}

// MFMA attention: one wave per (window, head); block = 4 waves.
__global__ __launch_bounds__(256) void attn_mfma_kernel(
    const __hip_bfloat16* __restrict__ qkv,
    const float* __restrict__ cbt,
    __hip_bfloat16* __restrict__ yout)
{
    __shared__ __bf16 P[4][64][PLD];
    const int tid = threadIdx.x;
    const int wave = tid >> 6, lane = tid & 63;
    const int bw = blockIdx.x >> 1;
    const int head = (blockIdx.x & 1) * 4 + wave;
    const int m16 = lane & 15, quad = lane >> 4;
    const int wi = bw & 255;
    const int hb = wi >> 3, wb = wi & 7;
    const int cls = ((hb == 31) ? 2 : 0) + ((wb == 7) ? 1 : 0);

    const __bf16* qb = (const __bf16*)qkv + (long)bw * TPW * 768 + head * 32;

    bf16x8 qf[4], kf[4];
#pragma unroll
    for (int i = 0; i < 4; ++i) {
        const int n = i * 16 + m16;
        bf16x8 q = {}, k = {};
        if (n < TPW) {
            const __bf16* p = qb + (long)n * 768 + quad * 8;
            q = *(const bf16x8*)p;
            k = *(const bf16x8*)(p + 256);
        }
        qf[i] = q; kf[i] = k;
    }

    bf16x8 vf[2][2];
#pragma unroll
    for (int jt = 0; jt < 2; ++jt)
#pragma unroll
        for (int kt = 0; kt < 2; ++kt) {
            bf16x8 v = {};
#pragma unroll
            for (int j = 0; j < 8; ++j) {
                const int tok = kt * 32 + quad * 8 + j;
                if (tok < TPW) v[j] = qb[(long)tok * 768 + 512 + jt * 16 + m16];
            }
            vf[jt][kt] = v;
        }

    // S = Q K^T (C-layout: lane holds S[n=i*16+quad*4+r][m=j*16+m16])
    f32x4 s[4][4] = {};
#pragma unroll
    for (int i = 0; i < 4; ++i)
#pragma unroll
        for (int j = 0; j < 4; ++j)
            s[i][j] = __builtin_amdgcn_mfma_f32_16x16x32_bf16(qf[i], kf[j], s[i][j], 0, 0, 0);

    const float* cb = cbt + (long)(cls * 8 + head) * 64 * 64;   // [m][n]
#pragma unroll
    for (int j = 0; j < 4; ++j) {
        const int m = j * 16 + m16;
#pragma unroll
        for (int i = 0; i < 4; ++i) {
            const float4 c = *(const float4*)(cb + m * 64 + i * 16 + quad * 4);
            s[i][j][0] = s[i][j][0] * 0.17677669529663687f + c.x;
            s[i][j][1] = s[i][j][1] * 0.17677669529663687f + c.y;
            s[i][j][2] = s[i][j][2] * 0.17677669529663687f + c.z;
            s[i][j][3] = s[i][j][3] * 0.17677669529663687f + c.w;
        }
    }

    // row softmax; normalized P -> LDS
#pragma unroll
    for (int i = 0; i < 4; ++i) {
#pragma unroll
        for (int r = 0; r < 4; ++r) {
            float mx = fmaxf(fmaxf(s[i][0][r], s[i][1][r]), fmaxf(s[i][2][r], s[i][3][r]));
            mx = fmaxf(mx, __shfl_xor(mx, 1));
            mx = fmaxf(mx, __shfl_xor(mx, 2));
            mx = fmaxf(mx, __shfl_xor(mx, 4));
            mx = fmaxf(mx, __shfl_xor(mx, 8));
            float sum = 0.0f;
#pragma unroll
            for (int j = 0; j < 4; ++j) {
                const float e = __expf(s[i][j][r] - mx);
                s[i][j][r] = e;
                sum += e;
            }
            sum += __shfl_xor(sum, 1);
            sum += __shfl_xor(sum, 2);
            sum += __shfl_xor(sum, 4);
            sum += __shfl_xor(sum, 8);
            const float inv = 1.0f / sum;
#pragma unroll
            for (int j = 0; j < 4; ++j)
                P[wave][i * 16 + quad * 4 + r][j * 16 + m16] = to_bf16(s[i][j][r] * inv);
        }
    }

    // O = P V, swapped operands: lane holds O[tok=i*16+m16][d=jt*16+quad*4+r]
    f32x4 o[4][2] = {};
#pragma unroll
    for (int kt = 0; kt < 2; ++kt)
#pragma unroll
        for (int i = 0; i < 4; ++i) {
            const bf16x8 pf = *(const bf16x8*)&P[wave][i * 16 + m16][kt * 32 + quad * 8];
#pragma unroll
            for (int jt = 0; jt < 2; ++jt)
                o[i][jt] = __builtin_amdgcn_mfma_f32_16x16x32_bf16(vf[jt][kt], pf, o[i][jt], 0, 0, 0);
        }

#pragma unroll
    for (int i = 0; i < 4; ++i) {
        const int tok = i * 16 + m16;
        if (tok < TPW) {
#pragma unroll
            for (int jt = 0; jt < 2; ++jt) {
                short4 pk;
                { __bf16 h = to_bf16(o[i][jt][0]); pk.x = *(short*)&h; }
                { __bf16 h = to_bf16(o[i][jt][1]); pk.y = *(short*)&h; }
                { __bf16 h = to_bf16(o[i][jt][2]); pk.z = *(short*)&h; }
                { __bf16 h = to_bf16(o[i][jt][3]); pk.w = *(short*)&h; }
                *(short4*)((short*)yout + ((long)bw * TPW + tok) * CDIM + head * 32 + jt * 16 + quad * 4) = pk;
            }
        }
    }
}

extern "C" void kernel_launch(void* const* d_in, const int* in_sizes, int n_in,
                              void* d_out, int out_size, void* d_ws, size_t ws_size,
                              hipStream_t stream) {
    (void)in_sizes; (void)n_in; (void)out_size; (void)ws_size;
    const float* x1     = (const float*)d_in[0];
    const float* n1g    = (const float*)d_in[2];
    const float* n1b    = (const float*)d_in[3];
    const float* qkv_w  = (const float*)d_in[4];
    const float* qkv_b  = (const float*)d_in[5];
    const float* proj_w = (const float*)d_in[6];
    const float* proj_b = (const float*)d_in[7];
    const float* rpb    = (const float*)d_in[8];
    const float* n2g    = (const float*)d_in[9];
    const float* n2b    = (const float*)d_in[10];
    const float* fc1_w  = (const float*)d_in[11];
    const float* fc1_b  = (const float*)d_in[12];
    const float* fc2_w  = (const float*)d_in[13];
    const float* fc2_b  = (const float*)d_in[14];

    float* out_x1 = (float*)d_out;
    float* out_y  = out_x1 + (long)MTOK * CDIM;

    char* ws = (char*)d_ws;
    const size_t SZ_A   = (size_t)MTOK * CDIM * sizeof(__hip_bfloat16);   // 25.7 MB
    const size_t SZ_BIG = (size_t)MTOK * 1024 * sizeof(__hip_bfloat16);   // 102.8 MB
    __hip_bfloat16* A    = (__hip_bfloat16*)ws;            // ln1 out -> yattn -> ln2 out
    char*           BIG  = ws + SZ_A;                      // qkv bf16 -> h1 bf16
    __hip_bfloat16* qkvb = (__hip_bfloat16*)BIG;
    __hip_bfloat16* H1   = (__hip_bfloat16*)BIG;
    __hip_bfloat16* wB   = (__hip_bfloat16*)(ws + SZ_A + SZ_BIG);
    __hip_bfloat16* qkv_wb  = wB;               // 196608
    __hip_bfloat16* proj_wb = wB + 196608;      // 65536
    __hip_bfloat16* fc1_wb  = wB + 262144;      // 262144
    __hip_bfloat16* fc2_wb  = wB + 524288;      // 262144
    float* cbt = (float*)(wB + 786432);         // 512 KB

    // 0) weights -> bf16 (one launch); combined bias/mask table
    castall_kernel<<<3072, 256, 0, stream>>>(qkv_w, proj_w, fc1_w, fc2_w, wB);
    cb_kernel<<<32, 256, 0, stream>>>(rpb, cbt);
    // 1) LN1 + roll + window partition (bf16)
    ln1_window_kernel<<<MTOK, 256, 0, stream>>>(x1, n1g, n1b, A);
    // 2) QKV gemm -> bf16
    gemm_mfma<0, __hip_bfloat16><<<dim3(768 / 128, MTOK / 128), 256, 0, stream>>>(
        A, qkv_wb, qkv_b, qkvb, MTOK, CDIM, 768, nullptr, nullptr);
    // 3) windowed attention (MFMA) -> bf16 (into A)
    attn_mfma_kernel<<<NWIN * 2, 256, 0, stream>>>(qkvb, cbt, A);
    // 4) proj + fused scatter: writes out_y and x1b (into out_x1)
    gemm_mfma<3, float><<<dim3(256 / 128, MTOK / 128), 256, 0, stream>>>(
        A, proj_wb, proj_b, out_x1, MTOK, CDIM, CDIM, x1, out_y);
    // 5) LN2 -> bf16 (into A)
    ln_kernel<<<MTOK, 256, 0, stream>>>(out_x1, n2g, n2b, A);
    // 6) fc1 + GELU -> bf16
    gemm_mfma<1, __hip_bfloat16><<<dim3(1024 / 128, MTOK / 128), 256, 0, stream>>>(
        A, fc1_wb, fc1_b, H1, MTOK, CDIM, 1024, nullptr, nullptr);
    // 7) fc2 + residual (in-place on out_x1)
    gemm_mfma<2, float><<<dim3(256 / 128, MTOK / 128), 256, 0, stream>>>(
        H1, fc2_wb, fc2_b, out_x1, MTOK, 1024, CDIM, out_x1, nullptr);
}